// Round 13
// baseline (1069.922 us; speedup 1.0000x reference)
//
#include <hip/hip_runtime.h>

namespace {
constexpr int UNITS = 2048;
constexpr int D_IN  = 96;
constexpr int BATCH = 64;
constexpr int T     = 512;
constexpr int NNZ   = 960;   // D_IN * C_IN
constexpr int C_REC = 10;
constexpr int NT    = 1024;  // threads/block; thread owns units 2t, 2t+1

// LDS arena (bytes). h ping/pong each hold TWO copies:
//   copy0: unit u at dword u
//   copy1: pair p=u>>1 at pair-slot p^((p>>4)&15)  (bank decorrelated)
constexpr int HA = 0;        // 2 x 8 KB
constexpr int HB = 16384;    // 2 x 8 KB
constexpr int IA = 32768;    // input_part ping (8 KB)
constexpr int IB = 40960;    // input_part pong (8 KB)
constexpr int LDS_BYTES = 49152;

// workspace (bytes)
constexpr int OFFS_OFS = 0;                        // u16 [20][1024] gather byte-offs
constexpr int WTAB_OFS = 20 * NT * 2;              // f32 [20][1024] @ 40960
constexpr int SCOL_OFS = WTAB_OFS + 20 * NT * 4;   // u16 [960] col byte-off @ 122880
constexpr int SROW_OFS = SCOL_OFS + NNZ * 2;       // u16 [960] row
constexpr int SVAL_OFS = SROW_OFS + NNZ * 2;       // f32 [960] val @ 126720
constexpr int WS_NEED  = SVAL_OFS + NNZ * 4;       // 130560 B
}

typedef float f32x2 __attribute__((ext_vector_type(2)));

// lgkm-only barrier: __syncthreads() drains vmcnt(0) -> would stall on the
// streaming out-stores and x prefetch loads every step.
__device__ __forceinline__ void bar_lds() {
  asm volatile("s_waitcnt lgkmcnt(0)\n\ts_barrier" ::: "memory");
}

__device__ __forceinline__ float fast_tanh(float x) {
  float e = __expf(2.0f * x);
  return 1.0f - __fdividef(2.0f, e + 1.0f);
}

// copy1 byte offset for unit idx (matches main kernel's publish pb1)
__device__ __forceinline__ int c1_byte(int idx) {
  int p = idx >> 1;
  return 8192 + (2 * (p ^ ((p >> 4) & 15)) + (idx & 1)) * 4;
}

// ---------------------------------------------------------------------------
// Prep (unchanged from R12): 17 blocks x 64 threads.
// Blocks 0..15: per-(wave, half) bank scheduling of gather slots; block 16:
// counting-sort scatter assignment of the 960 COO entries by column bank.
// ---------------------------------------------------------------------------
__global__ __launch_bounds__(64) void prep_sched(
    const int* __restrict__ ridx, const float* __restrict__ rvals,
    const int* __restrict__ krows, const int* __restrict__ kcols,
    const float* __restrict__ kvals,
    unsigned short* __restrict__ offs16, float* __restrict__ wtab,
    unsigned short* __restrict__ scol, unsigned short* __restrict__ srow,
    float* __restrict__ sval)
{
  const int l = threadIdx.x;
  if (blockIdx.x < 16) {
    const int w = blockIdx.x;
    __shared__ int   sidx[128 * C_REC];
    __shared__ float svalw[128 * C_REC];
    __shared__ int   hist[64];              // [half][bank]
    for (int i = l; i < 128 * C_REC; i += 64) {
      sidx[i]  = ridx[w * 128 * C_REC + i];
      svalw[i] = rvals[w * 128 * C_REC + i];
    }
    __syncthreads();
    const int tidm  = w * 64 + l;
    const int hbase = (l >> 5) << 5;
    const unsigned lh = ((unsigned)l * 2654435761u) >> 27;
    unsigned rem0 = 0x3FF, rem1 = 0x3FF;
    for (int s = 0; s < 20; ++s) {
      hist[l] = 0;
      __syncthreads();
      const int p = s & 1;
      unsigned& rem = p ? rem1 : rem0;
      const int ul = 2 * l + p;
      const unsigned m = rem;
      const int nc = 2 * __popc(m);
      int pe = -1, pidx = 0, pcp = 0;
      for (int r = 0; r < 8 && pe < 0; ++r) {
        const int thr = (r < 3) ? 1 : 2;
        const int rr  = (int)((r + lh) % (unsigned)nc);
        const int er = rr >> 1, cp = rr & 1;
        int cnt = 0, ce = 0;
#pragma unroll
        for (int e = 0; e < C_REC; ++e)
          if ((m >> e) & 1) { if (cnt == er) ce = e; ++cnt; }
        const int idx  = sidx[ul * C_REC + ce];
        const int byte = cp ? c1_byte(idx) : idx * 4;
        const int bank = (byte >> 2) & 31;
        const int old  = atomicAdd(&hist[hbase + bank], 1);
        if (old < thr || r == 7) { pe = ce; pcp = cp; pidx = idx; }
        else atomicSub(&hist[hbase + bank], 1);
      }
      rem = m & ~(1u << pe);
      offs16[s * NT + tidm] =
          (unsigned short)(pcp ? c1_byte(pidx) : pidx * 4);
      wtab[s * NT + tidm] = svalw[ul * C_REC + pe];
      __syncthreads();
    }
  } else {
    __shared__ int lc[64][32];
    __shared__ int base[64][32];
    __shared__ int tot[32];
    __shared__ int bankstart[32];
    for (int b2 = 0; b2 < 32; ++b2) lc[l][b2] = 0;
    __syncthreads();
    for (int k = 0; k < NNZ / 64; ++k)
      ++lc[l][kcols[l * (NNZ / 64) + k] & 31];
    __syncthreads();
    if (l < 32) {
      int run = 0;
      for (int t = 0; t < 64; ++t) { base[t][l] = run; run += lc[t][l]; }
      tot[l] = run;
    }
    __syncthreads();
    if (l == 0) {
      int run = 0;
      for (int b2 = 0; b2 < 32; ++b2) { bankstart[b2] = run; run += tot[b2]; }
    }
    for (int b2 = 0; b2 < 32; ++b2) lc[l][b2] = 0;
    __syncthreads();
    for (int k = 0; k < NNZ / 64; ++k) {
      const int i  = l * (NNZ / 64) + k;
      const int b2 = kcols[i] & 31;
      const int rank = bankstart[b2] + base[l][b2] + lc[l][b2]++;
      const int slot = rank % 30;
      const int li   = rank / 30;
      const int tid  = (slot >> 1) * 64 + (slot & 1) * 32 + li;
      scol[tid] = (unsigned short)(kcols[i] * 4);
      srow[tid] = (unsigned short)krows[i];
      sval[tid] = kvals[i];
    }
  }
}

// Hoist offsets AND fully precomputed LDS byte addresses for BOTH h buffers
// as named loop-invariant scalars: the compiler was recomputing smem+HC+off
// per gather per step (40 v_add/wave/step; VGPR_Count stuck at 40). With
// a##/c## (ping/pong addr sets) live across the loop, the unrolled body
// issues ds_read_b32 with zero address arithmetic.
#define RDECL(k)                                                               \
  const int oA##k = PERM ? (int)offs16[(2*(k)) * NT + tid]                     \
                         : ridx[u0 * C_REC + (k)] * 4;                         \
  const float wA##k = PERM ? wtab[(2*(k)) * NT + tid]                          \
                           : rvals[u0 * C_REC + (k)];                          \
  const int oB##k = PERM ? (int)offs16[(2*(k)+1) * NT + tid]                   \
                         : ridx[(u0 + 1) * C_REC + (k)] * 4;                   \
  const float wB##k = PERM ? wtab[(2*(k)+1) * NT + tid]                        \
                           : rvals[(u0 + 1) * C_REC + (k)];                    \
  const int aA##k = HA + oA##k;  /* gather addrs, h-ping */                    \
  const int aB##k = HA + oB##k;                                                \
  const int cA##k = HB + oA##k;  /* gather addrs, h-pong */                    \
  const int cB##k = HB + oB##k;

#define GATP(k)                                                                \
  s0 += *(const float*)(smem + aA##k) * wA##k;                                 \
  s1 += *(const float*)(smem + aB##k) * wB##k;
#define GATQ(k)                                                                \
  s0 += *(const float*)(smem + cA##k) * wA##k;                                 \
  s1 += *(const float*)(smem + cB##k) * wB##k;
#define GATP10 GATP(0) GATP(1) GATP(2) GATP(3) GATP(4)                         \
               GATP(5) GATP(6) GATP(7) GATP(8) GATP(9)
#define GATQ10 GATQ(0) GATQ(1) GATQ(2) GATQ(3) GATQ(4)                         \
               GATQ(5) GATQ(6) GATQ(7) GATQ(8) GATQ(9)

// One timestep. GATS = gather-address set (P gathers h-ping, Q h-pong);
// PUB0/PUB1 = precomputed publish addresses into the *other* h buffer;
// IR = input consumed (read + re-zero), IW = input built for t+1.
#define STEP(GATS, PUB0, PUB1, IR, IW, DO_SCATTER, TSTEP)                      \
  {                                                                            \
    f32x2 in2 = *(f32x2*)(smem + (IR) + tid * 8);                              \
    *(f32x2*)(smem + (IR) + tid * 8) = (f32x2){0.f, 0.f};                      \
    float s0 = in2.x + bias2.x;                                                \
    float s1 = in2.y + bias2.y;                                                \
    GATS                                                                       \
    if ((DO_SCATTER) && e0) atomicAdd((float*)(smem + (IW) + kcb), xn * kv);   \
    f32x2 hh = {fast_tanh(s0), fast_tanh(s1)};                                 \
    *(f32x2*)(smem + (PUB0)) = hh;                                             \
    *(f32x2*)(smem + (PUB1)) = hh;                                             \
    __builtin_nontemporal_store(hh, outp + (size_t)(TSTEP) * (UNITS / 2));     \
    if (e0) {                                                                  \
      int tnx = (TSTEP) + 2 < T ? (TSTEP) + 2 : T - 1;                         \
      xn = xin[tnx * D_IN + r0];                                               \
    }                                                                          \
    bar_lds();                                                                 \
  }

template <bool PERM>
__global__ __launch_bounds__(NT, 4) void reservoir_kernel(
    const float* __restrict__ inputs, const float* __restrict__ state0,
    const float* __restrict__ kvals,  const float* __restrict__ rvals,
    const float* __restrict__ bias,   const int* __restrict__ krows,
    const int* __restrict__ kcols,    const int* __restrict__ ridx,
    const unsigned short* __restrict__ offs16, const float* __restrict__ wtab,
    const unsigned short* __restrict__ scol,
    const unsigned short* __restrict__ srow, const float* __restrict__ sval,
    float* __restrict__ out)
{
  __shared__ __align__(16) char smem[LDS_BYTES];
  const int tid = threadIdx.x;
  const int b   = blockIdx.x;
  const int u0  = 2 * tid;

  // publish byte offsets (copy0 / copy1), precomputed for both h buffers
  const int pb0 = u0 * 4;
  const int pb1 = 8192 + (tid ^ ((tid >> 4) & 15)) * 8;
  const int pubP0 = HB + pb0, pubP1 = HB + pb1;   // ping-step publishes -> HB
  const int pubQ0 = HA + pb0, pubQ1 = HA + pb1;   // pong-step publishes -> HA

  // zero input ping+pong; stage h(0) into both copies of HA
  *(f32x2*)(smem + IA + tid * 8) = (f32x2){0.f, 0.f};
  *(f32x2*)(smem + IB + tid * 8) = (f32x2){0.f, 0.f};
  f32x2 h0 = *(const f32x2*)(state0 + b * UNITS + u0);
  *(f32x2*)(smem + pubQ0) = h0;
  *(f32x2*)(smem + pubQ1) = h0;

  RDECL(0) RDECL(1) RDECL(2) RDECL(3) RDECL(4)
  RDECL(5) RDECL(6) RDECL(7) RDECL(8) RDECL(9)

  const f32x2 bias2 = *(const f32x2*)(bias + u0);

  // input-kernel COO entry: bank-scheduled assignment (PERM) or raw COO
  const bool e0 = tid < NNZ;
  int r0 = 0, kcb = 0; float kv = 0.f;
  if (PERM) {
    if (e0) { r0 = srow[tid]; kcb = scol[tid]; kv = sval[tid]; }
  } else {
    if (e0) { r0 = krows[tid]; kcb = kcols[tid] * 4; kv = kvals[tid]; }
  }

  const float* xin  = inputs + (size_t)b * (T * D_IN);
  f32x2*       outp = (f32x2*)out + (size_t)b * (T * (UNITS / 2)) + tid;

  float xn = e0 ? xin[r0] : 0.f;    // x(0)
  __syncthreads();
  if (e0) atomicAdd((float*)(smem + IA + kcb), xn * kv);   // prime input(0)
  if (e0) xn = xin[D_IN + r0];      // x(1)
  bar_lds();

#pragma unroll 1
  for (int ts = 0; ts < T; ts += 2) {
    STEP(GATP10, pubP0, pubP1, IA, IB, true,         ts);
    STEP(GATQ10, pubQ0, pubQ1, IB, IA, (ts + 2) < T, ts + 1);
  }
}

extern "C" void kernel_launch(void* const* d_in, const int* in_sizes, int n_in,
                              void* d_out, int out_size, void* d_ws, size_t ws_size,
                              hipStream_t stream) {
  const float* inputs = (const float*)d_in[0];
  const float* state0 = (const float*)d_in[1];
  const float* kvals  = (const float*)d_in[2];
  const float* rvals  = (const float*)d_in[3];
  const float* bias   = (const float*)d_in[4];
  const int*   krows  = (const int*)d_in[5];
  const int*   kcols  = (const int*)d_in[6];
  const int*   ridx   = (const int*)d_in[7];

  unsigned short* offs16 = (unsigned short*)((char*)d_ws + OFFS_OFS);
  float*          wtab   = (float*)((char*)d_ws + WTAB_OFS);
  unsigned short* scol   = (unsigned short*)((char*)d_ws + SCOL_OFS);
  unsigned short* srow   = (unsigned short*)((char*)d_ws + SROW_OFS);
  float*          sval   = (float*)((char*)d_ws + SVAL_OFS);

  if (ws_size >= (size_t)WS_NEED) {
    prep_sched<<<dim3(17), dim3(64), 0, stream>>>(
        ridx, rvals, krows, kcols, kvals, offs16, wtab, scol, srow, sval);
    reservoir_kernel<true><<<dim3(BATCH), dim3(NT), 0, stream>>>(
        inputs, state0, kvals, rvals, bias, krows, kcols, ridx,
        offs16, wtab, scol, srow, sval, (float*)d_out);
  } else {
    reservoir_kernel<false><<<dim3(BATCH), dim3(NT), 0, stream>>>(
        inputs, state0, kvals, rvals, bias, krows, kcols, ridx,
        offs16, wtab, scol, srow, sval, (float*)d_out);
  }
}